// Round 3
// baseline (1479.595 us; speedup 1.0000x reference)
//
#include <hip/hip_runtime.h>
#include <hip/hip_bf16.h>

typedef unsigned short ushort_t;
typedef __bf16 bf16x8 __attribute__((ext_vector_type(8)));
typedef float f32x4 __attribute__((ext_vector_type(4)));
typedef short s16x8 __attribute__((ext_vector_type(8)));

__device__ __forceinline__ float b2f(ushort_t u) {
    union { unsigned u; float f; } x;
    x.u = ((unsigned)u) << 16;
    return x.f;
}
__device__ __forceinline__ ushort_t f2b(float f) {
    union { float f; unsigned u; } x;
    x.f = f;
    unsigned r = x.u + 0x7fffu + ((x.u >> 16) & 1u);
    return (ushort_t)(r >> 16);
}

// ---------- transpose fp32 -> bf16: dst[C][R] = bf16(src[R][C]^T) ----------
__global__ void transpose_k(const float* __restrict__ src, ushort_t* __restrict__ dst,
                            int R, int C) {
    long i = (long)blockIdx.x * 256 + threadIdx.x;
    if (i < (long)R * C) {
        int c = (int)(i / R);
        int r = (int)(i % R);
        dst[i] = f2b(src[(long)r * C + c]);
    }
}

// ---------- concat 3 fp32 bias vectors ----------
__global__ void concat3_k(const float* a, const float* b, const float* c,
                          float* dst, int n) {
    int i = blockIdx.x * 256 + threadIdx.x;
    if (i < 3 * n) dst[i] = (i < n) ? a[i] : (i < 2 * n ? b[i - n] : c[i - 2 * n]);
}

// ---------- LayerNorm over 512 fp32 elems per row -> bf16 out ----------
__global__ __launch_bounds__(256) void ln_kernel(
    const float* __restrict__ x, long xstride,
    const float* __restrict__ g, const float* __restrict__ be,
    ushort_t* __restrict__ out, long ostride) {
    int r = blockIdx.x, t = threadIdx.x;
    const float* row = x + (long)r * xstride;
    float2 p = *(const float2*)(row + 2 * t);
    float v0 = p.x, v1 = p.y;
    float s = v0 + v1, ss = v0 * v0 + v1 * v1;
#pragma unroll
    for (int off = 32; off; off >>= 1) {
        s += __shfl_xor(s, off, 64);
        ss += __shfl_xor(ss, off, 64);
    }
    __shared__ float sb[8];
    int w = t >> 6;
    if ((t & 63) == 0) { sb[w] = s; sb[4 + w] = ss; }
    __syncthreads();
    s = sb[0] + sb[1] + sb[2] + sb[3];
    ss = sb[4] + sb[5] + sb[6] + sb[7];
    float mean = s * (1.f / 512.f);
    float var = ss * (1.f / 512.f) - mean * mean;
    float rstd = rsqrtf(var + 1e-5f);
    float2 gp = *(const float2*)(g + 2 * t);
    float2 bp = *(const float2*)(be + 2 * t);
    ushort2 q;
    q.x = f2b((v0 - mean) * rstd * gp.x + bp.x);
    q.y = f2b((v1 - mean) * rstd * gp.y + bp.y);
    *(ushort2*)(out + (long)r * ostride + 2 * t) = q;
}

// ---------- MFMA GEMM: C[M,N] = A[M,K](bf16) * Bt[N,K](bf16)^T + bias(f32)
//            (+ res(f32)) (+relu); out bf16 or fp32 ----------
// block tile 128x128, 4 waves of 64x64 each, K-step 32.
__global__ __launch_bounds__(256) void gemm_kernel(
    const ushort_t* __restrict__ A, const ushort_t* __restrict__ Bt,
    const float* __restrict__ bias,
    const float* __restrict__ res, long res_stride,
    void* __restrict__ outp, long out_stride, int out_is_f32,
    int K, int relu) {
    __shared__ __align__(16) ushort_t lA[128 * 40];
    __shared__ __align__(16) ushort_t lB[128 * 40];
    const int t = threadIdx.x;
    const int m0 = blockIdx.x * 128, n0 = blockIdx.y * 128;
    const int wave = t >> 6, lane = t & 63, quad = lane >> 4, l16 = lane & 15;
    const int wm = (wave & 1) * 64, wn = (wave >> 1) * 64;
    f32x4 acc[4][4];
#pragma unroll
    for (int i = 0; i < 4; i++)
#pragma unroll
        for (int j = 0; j < 4; j++) acc[i][j] = (f32x4){0.f, 0.f, 0.f, 0.f};

    const int r0 = t >> 2;         // 0..63
    const int c0 = (t & 3) * 8;    // 0,8,16,24

    for (int k0 = 0; k0 < K; k0 += 32) {
        __syncthreads();
        *(s16x8*)&lA[r0 * 40 + c0] = *(const s16x8*)&A[(long)(m0 + r0) * K + k0 + c0];
        *(s16x8*)&lA[(r0 + 64) * 40 + c0] = *(const s16x8*)&A[(long)(m0 + r0 + 64) * K + k0 + c0];
        *(s16x8*)&lB[r0 * 40 + c0] = *(const s16x8*)&Bt[(long)(n0 + r0) * K + k0 + c0];
        *(s16x8*)&lB[(r0 + 64) * 40 + c0] = *(const s16x8*)&Bt[(long)(n0 + r0 + 64) * K + k0 + c0];
        __syncthreads();
        bf16x8 af[4], bfr[4];
#pragma unroll
        for (int i = 0; i < 4; i++) {
            af[i] = *(const bf16x8*)&lA[(wm + i * 16 + l16) * 40 + quad * 8];
            bfr[i] = *(const bf16x8*)&lB[(wn + i * 16 + l16) * 40 + quad * 8];
        }
#pragma unroll
        for (int i = 0; i < 4; i++)
#pragma unroll
            for (int j = 0; j < 4; j++)
                acc[i][j] = __builtin_amdgcn_mfma_f32_16x16x32_bf16(af[i], bfr[j], acc[i][j], 0, 0, 0);
    }
    // epilogue: D[row][col], row = quad*4+reg, col = lane&15 (per 16x16 tile)
#pragma unroll
    for (int i = 0; i < 4; i++) {
#pragma unroll
        for (int r = 0; r < 4; r++) {
            long row = m0 + wm + i * 16 + quad * 4 + r;
#pragma unroll
            for (int j = 0; j < 4; j++) {
                int col = n0 + wn + j * 16 + l16;
                float v = acc[i][j][r] + bias[col];
                if (res) v += res[row * res_stride + col];
                if (relu) v = fmaxf(v, 0.f);
                if (out_is_f32)
                    ((float*)outp)[row * out_stride + col] = v;
                else
                    ((ushort_t*)outp)[row * out_stride + col] = f2b(v);
            }
        }
    }
}

// ---------- dilated attention: simple direct-global version (bf16 in/out) ----------
// grid: 768 blocks. [0,512): group0 (s=512,r=1,heads0-3), [512,768): group1
// (s=1024,r=2,off=1,heads4-7). block=256; thread t owns q-row qhalf*256+t of
// the 512 attended rows of its (b,seg,head) unit. Key/value addresses are
// wave-uniform (L1 broadcast). Online softmax in chunks of 8 keys, fp32.
__global__ __launch_bounds__(256) void attn_kernel(const ushort_t* __restrict__ qkv,
                                                   ushort_t* __restrict__ o) {
    int bid = blockIdx.x;
    int t = threadIdx.x;
    int grp, b, h, seg, qhalf;
    if (bid < 512) {
        grp = 0; qhalf = bid & 1; seg = (bid >> 1) & 15; h = (bid >> 5) & 3; b = bid >> 7;
    } else {
        int u = bid - 512;
        grp = 1; qhalf = u & 1; seg = (u >> 1) & 7; h = (u >> 4) & 3; b = u >> 6;
    }
    int habs = grp * 4 + h;
    int qi = qhalf * 256 + t;  // 0..511 attended index
    long segbase = (grp == 0) ? (long)seg * 512 : (long)seg * 1024 + 1;
    int stok = 1 + grp;  // dilation stride
    long btok = (long)b * 8192;
    long qrow = btok + segbase + (long)stok * qi;
    const ushort_t* qp = qkv + qrow * 1536 + habs * 64;
    float q[64];
#pragma unroll
    for (int d = 0; d < 64; d += 2) {
        ushort2 p = *(const ushort2*)(qp + d);
        q[d] = b2f(p.x) * 0.125f;
        q[d + 1] = b2f(p.y) * 0.125f;
    }
    float m = -1e30f, l = 0.f, oacc[64];
#pragma unroll
    for (int d = 0; d < 64; d++) oacc[d] = 0.f;

    for (int c = 0; c < 64; c++) {  // 64 chunks of 8 keys
        float s[8];
#pragma unroll
        for (int jj = 0; jj < 8; jj++) {
            long rb = (btok + segbase + (long)stok * (c * 8 + jj)) * 1536 + habs * 64;
            const ushort_t* kp = qkv + rb + 512;
            float a = 0.f;
#pragma unroll
            for (int d = 0; d < 64; d += 2) {
                ushort2 kk = *(const ushort2*)(kp + d);
                a += q[d] * b2f(kk.x) + q[d + 1] * b2f(kk.y);
            }
            s[jj] = a;
        }
        float cm = m;
#pragma unroll
        for (int jj = 0; jj < 8; jj++) cm = fmaxf(cm, s[jj]);
        float corr = __expf(m - cm);
        l *= corr;
#pragma unroll
        for (int d = 0; d < 64; d++) oacc[d] *= corr;
#pragma unroll
        for (int jj = 0; jj < 8; jj++) {
            float p = __expf(s[jj] - cm);
            l += p;
            long rb = (btok + segbase + (long)stok * (c * 8 + jj)) * 1536 + habs * 64;
            const ushort_t* vp = qkv + rb + 1024;
#pragma unroll
            for (int d = 0; d < 64; d += 2) {
                ushort2 vv = *(const ushort2*)(vp + d);
                oacc[d] += p * b2f(vv.x);
                oacc[d + 1] += p * b2f(vv.y);
            }
        }
        m = cm;
    }
    float inv = 1.f / l;
    ushort_t* op = o + qrow * 512 + habs * 64;
#pragma unroll
    for (int d = 0; d < 64; d += 2) {
        ushort2 w;
        w.x = f2b(oacc[d] * inv);
        w.y = f2b(oacc[d + 1] * inv);
        *(ushort2*)(op + d) = w;
    }
}

extern "C" void kernel_launch(void* const* d_in, const int* in_sizes, int n_in,
                              void* d_out, int out_size, void* d_ws, size_t ws_size,
                              hipStream_t stream) {
    const float* x    = (const float*)d_in[0];
    const float* ln1g = (const float*)d_in[1];
    const float* ln1b = (const float*)d_in[2];
    const float* Wq   = (const float*)d_in[3];
    const float* bq   = (const float*)d_in[4];
    const float* Wk   = (const float*)d_in[5];
    const float* bk   = (const float*)d_in[6];
    const float* Wv   = (const float*)d_in[7];
    const float* bv   = (const float*)d_in[8];
    const float* Wo   = (const float*)d_in[9];
    const float* bo   = (const float*)d_in[10];
    const float* ln2g = (const float*)d_in[11];
    const float* ln2b = (const float*)d_in[12];
    const float* W1   = (const float*)d_in[13];
    const float* b1   = (const float*)d_in[14];
    const float* W2   = (const float*)d_in[15];
    const float* b2   = (const float*)d_in[16];
    float* out = (float*)d_out;
    char* ws = (char*)d_ws;

    // workspace (bytes):
    //  [0,32M):      XN (bf16) -> then O -> then H (sequential reuse)
    //  [32M,128M):   QKV (bf16, 96M) -> then ACT (64M)
    //  [128M,...):   bf16 transposed weights + fp32 concat bias
    const size_t NEED = 134217728ull + 1572864 + 524288 + 1048576 + 1048576 + 8192;
    if (ws_size < NEED) return;

    ushort_t* XN    = (ushort_t*)(ws + 0);
    ushort_t* QKV   = (ushort_t*)(ws + 33554432);
    ushort_t* O     = XN;
    ushort_t* H     = XN;
    ushort_t* ACT   = QKV;
    ushort_t* WQKVT = (ushort_t*)(ws + 134217728);
    ushort_t* WOT   = WQKVT + 786432;   // 1536*512 elems
    ushort_t* W1T   = WOT + 262144;     // 512*512
    ushort_t* W2T   = W1T + 524288;     // 1024*512
    float*    BQKV  = (float*)(W2T + 524288);  // 1536 fp32

    transpose_k<<<1024, 256, 0, stream>>>(Wq, WQKVT, 512, 512);
    transpose_k<<<1024, 256, 0, stream>>>(Wk, WQKVT + 262144, 512, 512);
    transpose_k<<<1024, 256, 0, stream>>>(Wv, WQKVT + 524288, 512, 512);
    transpose_k<<<1024, 256, 0, stream>>>(Wo, WOT, 512, 512);
    transpose_k<<<2048, 256, 0, stream>>>(W1, W1T, 512, 1024);
    transpose_k<<<2048, 256, 0, stream>>>(W2, W2T, 1024, 512);
    concat3_k<<<6, 256, 0, stream>>>(bq, bk, bv, BQKV, 512);

    // LN1 on x2 = x[..., 512:1024]  (fp32 in, bf16 out)
    ln_kernel<<<32768, 256, 0, stream>>>(x + 512, 1024, ln1g, ln1b, XN, 512);
    // fused QKV projection: [32768,512] x [512,1536] -> bf16 QKV
    gemm_kernel<<<dim3(256, 12), 256, 0, stream>>>(XN, WQKVT, BQKV, nullptr, 0,
                                                   QKV, 1536, 0, 512, 0);
    // zero attention output (heads 4-7 even positions must stay 0)
    hipMemsetAsync(O, 0, 33554432, stream);
    attn_kernel<<<768, 256, 0, stream>>>(QKV, O);
    // y1 = x1 + O @ Wo + bo -> out[:, 0:512]  (fp32 out)
    gemm_kernel<<<dim3(256, 4), 256, 0, stream>>>(O, WOT, bo, x, 1024,
                                                  out, 1024, 1, 512, 0);
    // LN2 on y1 (fp32 from out) -> bf16 H
    ln_kernel<<<32768, 256, 0, stream>>>(out, 1024, ln2g, ln2b, H, 512);
    // FFN1: relu(h @ W1 + b1) -> bf16 ACT
    gemm_kernel<<<dim3(256, 8), 256, 0, stream>>>(H, W1T, b1, nullptr, 0,
                                                  ACT, 1024, 0, 512, 1);
    // FFN2: y2 = x2 + act @ W2 + b2 -> out[:, 512:1024] (fp32 out)
    gemm_kernel<<<dim3(256, 4), 256, 0, stream>>>(ACT, W2T, b2, x + 512, 1024,
                                                  out + 512, 1024, 1, 1024, 0);
}

// Round 4
// 787.701 us; speedup vs baseline: 1.8784x; 1.8784x over previous
//
#include <hip/hip_runtime.h>
#include <hip/hip_bf16.h>

typedef unsigned short ushort_t;
typedef __bf16 bf16x8 __attribute__((ext_vector_type(8)));
typedef float f32x4 __attribute__((ext_vector_type(4)));
typedef short s16x8 __attribute__((ext_vector_type(8)));

__device__ __forceinline__ float b2f(ushort_t u) {
    union { unsigned u; float f; } x;
    x.u = ((unsigned)u) << 16;
    return x.f;
}
__device__ __forceinline__ ushort_t f2b(float f) {
    union { float f; unsigned u; } x;
    x.f = f;
    unsigned r = x.u + 0x7fffu + ((x.u >> 16) & 1u);
    return (ushort_t)(r >> 16);
}

// ---------- transpose fp32 -> bf16: dst[C][R] = bf16(src[R][C]^T) ----------
__global__ void transpose_k(const float* __restrict__ src, ushort_t* __restrict__ dst,
                            int R, int C) {
    long i = (long)blockIdx.x * 256 + threadIdx.x;
    if (i < (long)R * C) {
        int c = (int)(i / R);
        int r = (int)(i % R);
        dst[i] = f2b(src[(long)r * C + c]);
    }
}

// ---------- concat 3 fp32 bias vectors ----------
__global__ void concat3_k(const float* a, const float* b, const float* c,
                          float* dst, int n) {
    int i = blockIdx.x * 256 + threadIdx.x;
    if (i < 3 * n) dst[i] = (i < n) ? a[i] : (i < 2 * n ? b[i - n] : c[i - 2 * n]);
}

// ---------- LayerNorm over 512 fp32 elems per row -> bf16 out ----------
__global__ __launch_bounds__(256) void ln_kernel(
    const float* __restrict__ x, long xstride,
    const float* __restrict__ g, const float* __restrict__ be,
    ushort_t* __restrict__ out, long ostride) {
    int r = blockIdx.x, t = threadIdx.x;
    const float* row = x + (long)r * xstride;
    float2 p = *(const float2*)(row + 2 * t);
    float v0 = p.x, v1 = p.y;
    float s = v0 + v1, ss = v0 * v0 + v1 * v1;
#pragma unroll
    for (int off = 32; off; off >>= 1) {
        s += __shfl_xor(s, off, 64);
        ss += __shfl_xor(ss, off, 64);
    }
    __shared__ float sb[8];
    int w = t >> 6;
    if ((t & 63) == 0) { sb[w] = s; sb[4 + w] = ss; }
    __syncthreads();
    s = sb[0] + sb[1] + sb[2] + sb[3];
    ss = sb[4] + sb[5] + sb[6] + sb[7];
    float mean = s * (1.f / 512.f);
    float var = ss * (1.f / 512.f) - mean * mean;
    float rstd = rsqrtf(var + 1e-5f);
    float2 gp = *(const float2*)(g + 2 * t);
    float2 bp = *(const float2*)(be + 2 * t);
    ushort2 q;
    q.x = f2b((v0 - mean) * rstd * gp.x + bp.x);
    q.y = f2b((v1 - mean) * rstd * gp.y + bp.y);
    *(ushort2*)(out + (long)r * ostride + 2 * t) = q;
}

// ---------- MFMA GEMM: C[M,N] = A[M,K](bf16) * Bt[N,K](bf16)^T + bias(f32)
//            (+ res(f32)) (+relu); out bf16 or fp32 ----------
__global__ __launch_bounds__(256) void gemm_kernel(
    const ushort_t* __restrict__ A, const ushort_t* __restrict__ Bt,
    const float* __restrict__ bias,
    const float* __restrict__ res, long res_stride,
    void* __restrict__ outp, long out_stride, int out_is_f32,
    int K, int relu) {
    __shared__ __align__(16) ushort_t lA[128 * 40];
    __shared__ __align__(16) ushort_t lB[128 * 40];
    const int t = threadIdx.x;
    const int m0 = blockIdx.x * 128, n0 = blockIdx.y * 128;
    const int wave = t >> 6, lane = t & 63, quad = lane >> 4, l16 = lane & 15;
    const int wm = (wave & 1) * 64, wn = (wave >> 1) * 64;
    f32x4 acc[4][4];
#pragma unroll
    for (int i = 0; i < 4; i++)
#pragma unroll
        for (int j = 0; j < 4; j++) acc[i][j] = (f32x4){0.f, 0.f, 0.f, 0.f};

    const int r0 = t >> 2;
    const int c0 = (t & 3) * 8;

    for (int k0 = 0; k0 < K; k0 += 32) {
        __syncthreads();
        *(s16x8*)&lA[r0 * 40 + c0] = *(const s16x8*)&A[(long)(m0 + r0) * K + k0 + c0];
        *(s16x8*)&lA[(r0 + 64) * 40 + c0] = *(const s16x8*)&A[(long)(m0 + r0 + 64) * K + k0 + c0];
        *(s16x8*)&lB[r0 * 40 + c0] = *(const s16x8*)&Bt[(long)(n0 + r0) * K + k0 + c0];
        *(s16x8*)&lB[(r0 + 64) * 40 + c0] = *(const s16x8*)&Bt[(long)(n0 + r0 + 64) * K + k0 + c0];
        __syncthreads();
        bf16x8 af[4], bfr[4];
#pragma unroll
        for (int i = 0; i < 4; i++) {
            af[i] = *(const bf16x8*)&lA[(wm + i * 16 + l16) * 40 + quad * 8];
            bfr[i] = *(const bf16x8*)&lB[(wn + i * 16 + l16) * 40 + quad * 8];
        }
#pragma unroll
        for (int i = 0; i < 4; i++)
#pragma unroll
            for (int j = 0; j < 4; j++)
                acc[i][j] = __builtin_amdgcn_mfma_f32_16x16x32_bf16(af[i], bfr[j], acc[i][j], 0, 0, 0);
    }
#pragma unroll
    for (int i = 0; i < 4; i++) {
#pragma unroll
        for (int r = 0; r < 4; r++) {
            long row = m0 + wm + i * 16 + quad * 4 + r;
#pragma unroll
            for (int j = 0; j < 4; j++) {
                int col = n0 + wn + j * 16 + l16;
                float v = acc[i][j][r] + bias[col];
                if (res) v += res[row * res_stride + col];
                if (relu) v = fmaxf(v, 0.f);
                if (out_is_f32)
                    ((float*)outp)[row * out_stride + col] = v;
                else
                    ((ushort_t*)outp)[row * out_stride + col] = f2b(v);
            }
        }
    }
}

// ---------- dilated attention: MFMA flash version ----------
// grid 1536: [0,1024): group0 (s=512,r=1,heads0-3), [1024,1536): group1
// (s=1024,r=2,off=1,heads4-7). Block = 4 waves; each wave owns 32 q-rows
// (2 m-tiles of 16); block covers 128 of the unit's 512 attended rows.
// Loop over 8 chunks of 64 keys: S = Q K^T (MFMA, keys as N), online softmax
// (shfl over l16 lanes), P -> per-wave LDS (C/D -> A layout), O += P V (MFMA,
// V^T staged in LDS with XOR-octet swizzle).
__global__ __launch_bounds__(256) void attn_kernel(const ushort_t* __restrict__ qkv,
                                                   ushort_t* __restrict__ o) {
    __shared__ __align__(16) ushort_t lK[64 * 72];       // [key][dim]
    __shared__ __align__(16) ushort_t lV[64 * 72];       // [dim][key^swz]
    __shared__ __align__(16) ushort_t lP[4 * 32 * 72];   // per-wave [qrow][key]

    const int bid = blockIdx.x;
    const int t = threadIdx.x;
    int grp, b, h, seg, qblk;
    if (bid < 1024) {
        grp = 0; qblk = bid & 3; seg = (bid >> 2) & 15; h = (bid >> 6) & 3; b = bid >> 8;
    } else {
        int u = bid - 1024;
        grp = 1; qblk = u & 3; seg = (u >> 2) & 7; h = (u >> 5) & 3; b = u >> 7;
    }
    const int habs = grp * 4 + h;
    const long segbase = (grp == 0) ? (long)seg * 512 : (long)seg * 1024 + 1;
    const int stok = 1 + grp;
    const long btok = (long)b * 8192;
    const int q0 = qblk * 128;

    const int wave = t >> 6, lane = t & 63, quad = lane >> 4, l16 = lane & 15;
    ushort_t* lPw = lP + wave * 32 * 72;

    // Q fragments: qf[m][ks], A-layout [m=l16][k=quad*8+j]
    bf16x8 qf[2][2];
#pragma unroll
    for (int m = 0; m < 2; m++) {
        long tok = btok + segbase + (long)stok * (q0 + wave * 32 + m * 16 + l16);
        const ushort_t* qp = qkv + tok * 1536 + habs * 64;
        qf[m][0] = *(const bf16x8*)(qp + quad * 8);
        qf[m][1] = *(const bf16x8*)(qp + 32 + quad * 8);
    }

    f32x4 oacc[2][4];
#pragma unroll
    for (int m = 0; m < 2; m++)
#pragma unroll
        for (int n = 0; n < 4; n++) oacc[m][n] = (f32x4){0.f, 0.f, 0.f, 0.f};
    float mst[2][4], lst[2][4];
#pragma unroll
    for (int m = 0; m < 2; m++)
#pragma unroll
        for (int r = 0; r < 4; r++) { mst[m][r] = -1e30f; lst[m][r] = 0.f; }

    const int skey = t >> 2;      // staging: key 0..63
    const int sdg = t & 3;        // dim group (16 dims)

    for (int c = 0; c < 8; c++) {
        // load K/V chunk to regs
        long ktok = btok + segbase + (long)stok * (c * 64 + skey);
        const ushort_t* kp = qkv + ktok * 1536 + 512 + habs * 64 + sdg * 16;
        s16x8 kr0 = *(const s16x8*)kp;
        s16x8 kr1 = *(const s16x8*)(kp + 8);
        s16x8 vr0 = *(const s16x8*)(kp + 512);
        s16x8 vr1 = *(const s16x8*)(kp + 520);
        __syncthreads();  // previous chunk fully consumed
        *(s16x8*)&lK[skey * 72 + sdg * 16] = kr0;
        *(s16x8*)&lK[skey * 72 + sdg * 16 + 8] = kr1;
#pragma unroll
        for (int i = 0; i < 8; i++) {
            int d0 = sdg * 16 + i, d1 = sdg * 16 + 8 + i;
            lV[d0 * 72 + (skey ^ (((d0 >> 3) & 7) * 8))] = (ushort_t)vr0[i];
            lV[d1 * 72 + (skey ^ (((d1 >> 3) & 7) * 8))] = (ushort_t)vr1[i];
        }
        __syncthreads();

        // S = Q K^T, softmax, write P
#pragma unroll
        for (int m = 0; m < 2; m++) {
            f32x4 sa[4];
#pragma unroll
            for (int n = 0; n < 4; n++) sa[n] = (f32x4){0.f, 0.f, 0.f, 0.f};
#pragma unroll
            for (int ks = 0; ks < 2; ks++)
#pragma unroll
                for (int n = 0; n < 4; n++) {
                    bf16x8 kf = *(const bf16x8*)&lK[(n * 16 + l16) * 72 + ks * 32 + quad * 8];
                    sa[n] = __builtin_amdgcn_mfma_f32_16x16x32_bf16(qf[m][ks], kf, sa[n], 0, 0, 0);
                }
#pragma unroll
            for (int r = 0; r < 4; r++) {
                float mx = fmaxf(fmaxf(sa[0][r], sa[1][r]), fmaxf(sa[2][r], sa[3][r]));
                mx = fmaxf(mx, __shfl_xor(mx, 1, 64));
                mx = fmaxf(mx, __shfl_xor(mx, 2, 64));
                mx = fmaxf(mx, __shfl_xor(mx, 4, 64));
                mx = fmaxf(mx, __shfl_xor(mx, 8, 64));
                mx *= 0.125f;
                float mold = mst[m][r];
                float mnew = fmaxf(mold, mx);
                float alpha = __expf(mold - mnew);
                float rsum = 0.f;
#pragma unroll
                for (int n = 0; n < 4; n++) {
                    float p = __expf(fmaf(sa[n][r], 0.125f, -mnew));
                    rsum += p;
                    sa[n][r] = p;
                }
                rsum += __shfl_xor(rsum, 1, 64);
                rsum += __shfl_xor(rsum, 2, 64);
                rsum += __shfl_xor(rsum, 4, 64);
                rsum += __shfl_xor(rsum, 8, 64);
                lst[m][r] = lst[m][r] * alpha + rsum;
                mst[m][r] = mnew;
#pragma unroll
                for (int n = 0; n < 4; n++) oacc[m][n][r] *= alpha;
            }
#pragma unroll
            for (int r = 0; r < 4; r++)
#pragma unroll
                for (int n = 0; n < 4; n++)
                    lPw[(m * 16 + quad * 4 + r) * 72 + n * 16 + l16] = f2b(sa[n][r]);
        }
        __asm__ volatile("s_waitcnt lgkmcnt(0)" ::: "memory");  // P visible to own wave

        // O += P V
#pragma unroll
        for (int m = 0; m < 2; m++) {
            bf16x8 pf[2];
#pragma unroll
            for (int ks = 0; ks < 2; ks++)
                pf[ks] = *(const bf16x8*)&lPw[(m * 16 + l16) * 72 + ks * 32 + quad * 8];
#pragma unroll
            for (int n = 0; n < 4; n++) {
                int shift = ((n * 2 + (l16 >> 3)) & 7) * 8;
#pragma unroll
                for (int ks = 0; ks < 2; ks++) {
                    int kcol = (ks * 32 + quad * 8) ^ shift;
                    bf16x8 vf = *(const bf16x8*)&lV[(n * 16 + l16) * 72 + kcol];
                    oacc[m][n] = __builtin_amdgcn_mfma_f32_16x16x32_bf16(pf[ks], vf, oacc[m][n], 0, 0, 0);
                }
            }
        }
    }

    // epilogue
#pragma unroll
    for (int m = 0; m < 2; m++) {
#pragma unroll
        for (int r = 0; r < 4; r++) {
            float inv = 1.f / lst[m][r];
            long tok = btok + segbase + (long)stok * (q0 + wave * 32 + m * 16 + quad * 4 + r);
            ushort_t* op = o + tok * 512 + habs * 64;
#pragma unroll
            for (int n = 0; n < 4; n++) op[n * 16 + l16] = f2b(oacc[m][n][r] * inv);
        }
    }
}

extern "C" void kernel_launch(void* const* d_in, const int* in_sizes, int n_in,
                              void* d_out, int out_size, void* d_ws, size_t ws_size,
                              hipStream_t stream) {
    const float* x    = (const float*)d_in[0];
    const float* ln1g = (const float*)d_in[1];
    const float* ln1b = (const float*)d_in[2];
    const float* Wq   = (const float*)d_in[3];
    const float* bq   = (const float*)d_in[4];
    const float* Wk   = (const float*)d_in[5];
    const float* bk   = (const float*)d_in[6];
    const float* Wv   = (const float*)d_in[7];
    const float* bv   = (const float*)d_in[8];
    const float* Wo   = (const float*)d_in[9];
    const float* bo   = (const float*)d_in[10];
    const float* ln2g = (const float*)d_in[11];
    const float* ln2b = (const float*)d_in[12];
    const float* W1   = (const float*)d_in[13];
    const float* b1   = (const float*)d_in[14];
    const float* W2   = (const float*)d_in[15];
    const float* b2   = (const float*)d_in[16];
    float* out = (float*)d_out;
    char* ws = (char*)d_ws;

    const size_t NEED = 134217728ull + 1572864 + 524288 + 1048576 + 1048576 + 8192;
    if (ws_size < NEED) return;

    ushort_t* XN    = (ushort_t*)(ws + 0);
    ushort_t* QKV   = (ushort_t*)(ws + 33554432);
    ushort_t* O     = XN;
    ushort_t* H     = XN;
    ushort_t* ACT   = QKV;
    ushort_t* WQKVT = (ushort_t*)(ws + 134217728);
    ushort_t* WOT   = WQKVT + 786432;
    ushort_t* W1T   = WOT + 262144;
    ushort_t* W2T   = W1T + 524288;
    float*    BQKV  = (float*)(W2T + 524288);

    transpose_k<<<1024, 256, 0, stream>>>(Wq, WQKVT, 512, 512);
    transpose_k<<<1024, 256, 0, stream>>>(Wk, WQKVT + 262144, 512, 512);
    transpose_k<<<1024, 256, 0, stream>>>(Wv, WQKVT + 524288, 512, 512);
    transpose_k<<<1024, 256, 0, stream>>>(Wo, WOT, 512, 512);
    transpose_k<<<2048, 256, 0, stream>>>(W1, W1T, 512, 1024);
    transpose_k<<<2048, 256, 0, stream>>>(W2, W2T, 1024, 512);
    concat3_k<<<6, 256, 0, stream>>>(bq, bk, bv, BQKV, 512);

    ln_kernel<<<32768, 256, 0, stream>>>(x + 512, 1024, ln1g, ln1b, XN, 512);
    gemm_kernel<<<dim3(256, 12), 256, 0, stream>>>(XN, WQKVT, BQKV, nullptr, 0,
                                                   QKV, 1536, 0, 512, 0);
    hipMemsetAsync(O, 0, 33554432, stream);
    attn_kernel<<<1536, 256, 0, stream>>>(QKV, O);
    gemm_kernel<<<dim3(256, 4), 256, 0, stream>>>(O, WOT, bo, x, 1024,
                                                  out, 1024, 1, 512, 0);
    ln_kernel<<<32768, 256, 0, stream>>>(out, 1024, ln2g, ln2b, H, 512);
    gemm_kernel<<<dim3(256, 8), 256, 0, stream>>>(H, W1T, b1, nullptr, 0,
                                                  ACT, 1024, 0, 512, 1);
    gemm_kernel<<<dim3(256, 4), 256, 0, stream>>>(ACT, W2T, b2, x + 512, 1024,
                                                  out + 512, 1024, 1, 1024, 0);
}